// Round 3
// baseline (1877.447 us; speedup 1.0000x reference)
//
#include <hip/hip_runtime.h>
#include <math.h>

#define SS 9
#define EE 32
#define PTPB 256   // prep kernel block size
#define ATPB 64    // attn kernel: ONE WAVE per block

// d_ws float offsets (derived weights, computed by prep kernel each launch)
#define WS_M0   0      // M_h[e][e2], h-major, 2*1024
#define WS_PT0  2048   // PT_h[e][f] = P_h[f][e], 2*1024
#define WS_UB   4096   // ub_h[e],  2*32
#define WS_U    4160   // u_h[e],   2*32
#define WS_BO2  4224   // bo2[f],   32
#define WS_C    4256   // c_h,      2

// qk[h][s]*0.25-scale is folded:
//   0.25*qk = c_h + q.u_h + k_s.(ub_h + q^T M_h)
//   out[f]  = bo2[f] + sum_h vbar_h . PT_h[:,f]   (uses sum_s p = 1)
__global__ void gauss_prep_kernel(const float* __restrict__ ipw,
                                  const float* __restrict__ ipb,
                                  const float* __restrict__ opw,
                                  const float* __restrict__ opb,
                                  float* __restrict__ dw) {
  const int tid = threadIdx.x;
  for (int idx = tid; idx < 2048; idx += PTPB) {
    const int h = idx >> 10, e = (idx >> 5) & 31, e2 = idx & 31;
    float acc = 0.f;
    for (int d = 0; d < 16; ++d)
      acc += ipw[(h * 16 + d) * 32 + e] * ipw[(32 + h * 16 + d) * 32 + e2];
    dw[WS_M0 + idx] = 0.25f * acc;
  }
  for (int idx = tid; idx < 2048; idx += PTPB) {
    const int h = idx >> 10, e = (idx >> 5) & 31, f = idx & 31;
    float acc = 0.f;
    for (int d = 0; d < 16; ++d)
      acc += opw[f * 32 + h * 16 + d] * ipw[(64 + h * 16 + d) * 32 + e];
    dw[WS_PT0 + idx] = acc;
  }
  if (tid < 64) {
    const int h = tid >> 5, e = tid & 31;
    float a_ub = 0.f, a_u = 0.f;
    for (int d = 0; d < 16; ++d) {
      a_ub += ipb[h * 16 + d] * ipw[(32 + h * 16 + d) * 32 + e];
      a_u  += ipw[(h * 16 + d) * 32 + e] * ipb[32 + h * 16 + d];
    }
    dw[WS_UB + tid] = 0.25f * a_ub;
    dw[WS_U + tid]  = 0.25f * a_u;
  } else if (tid < 96) {
    const int f = tid - 64;
    float acc = opb[f];
    for (int j = 0; j < 32; ++j) acc += ipb[64 + j] * opw[f * 32 + j];
    dw[WS_BO2 + f] = acc;
  } else if (tid < 98) {
    const int h = tid - 96;
    float acc = 0.f;
    for (int d = 0; d < 16; ++d) acc += ipb[h * 16 + d] * ipb[32 + h * 16 + d];
    dw[WS_C + h] = 0.25f * acc;
  }
}

// async HBM -> LDS, 16B per lane, zero VGPR staging cost
__device__ __forceinline__ void load16(const float* g, float4* l) {
  __builtin_amdgcn_global_load_lds(
      (const __attribute__((address_space(1))) void*)g,
      (__attribute__((address_space(3))) void*)l, 16, 0, 0);
}

// One wave per block, two private 8KB slice buffers, 19-slice pipeline
// (Q, K0..K8, V0..V8) issued 2 ahead with counted vmcnt(8) — never 0 in
// the main loop. gload_lds dest is linear (HW: base+lane*16); the source
// address is pre-swizzled so slot (r<<3)|jslot holds chunk jslot^(r&7);
// reads use the same involution -> conflict-free ds_read_b128 both ways.
__global__ __launch_bounds__(ATPB, 2) void gauss_attn_kernel(
    const float* __restrict__ query,
    const float* __restrict__ key,
    const float* __restrict__ value,
    const float* __restrict__ gauss,
    const float* __restrict__ dw,
    float* __restrict__ out) {
  __shared__ float4 kt[2][512];   // 2 x 8KB = 16KB -> 10 blocks/CU

  const int l = threadIdx.x;      // 0..63, also this thread's row-in-wave
  const int g = l >> 3;           // staging row-group (r&7 of staged rows)
  const int c = l & 7;            // staging chunk-slot
  const int sw = c ^ g;           // chunk to fetch so slot c holds it
  const long rb = (long)blockIdx.x * ATPB;

  // per-lane swizzled global bases (row rb+g, chunk sw; +8 rows per i)
  const float* qs   = query + (rb + g) * EE + sw * 4;
  const float* ks   = key   + (rb + g) * (long)(SS * EE) + sw * 4;
  const float* vsrc = value + (rb + g) * (long)(SS * EE) + sw * 4;

  // gauss: tiny (36B/row), read per-thread
  float gw[SS];
  {
    const float* gp = gauss + (rb + l) * SS;
    #pragma unroll
    for (int s = 0; s < SS; ++s) gw[s] = gp[s];
  }

  // slice u=0 (Q) -> buf0, u=1 (K0) -> buf1
  #pragma unroll
  for (int i = 0; i < 8; ++i) load16(qs + i * (8 * EE), &kt[0][i * 64]);
  #pragma unroll
  for (int i = 0; i < 8; ++i) load16(ks + i * (8 * SS * EE), &kt[1][i * 64]);

  // consume Q (allow K0's 8 outstanding)
  asm volatile("s_waitcnt vmcnt(8)" ::: "memory");
  float qreg[32];
  #pragma unroll
  for (int j = 0; j < 8; ++j) {
    const float4 v = kt[0][(l << 3) | (j ^ c)];
    qreg[4*j] = v.x; qreg[4*j+1] = v.y; qreg[4*j+2] = v.z; qreg[4*j+3] = v.w;
  }
  // u=2 (K1) -> buf0
  #pragma unroll
  for (int i = 0; i < 8; ++i) load16(ks + EE + i * (8 * SS * EE), &kt[0][i * 64]);

  // t0[h] = c_h + q.u_h ; wv_h = ub_h + q^T M_h  (K0/K1 fly under this)
  float t00 = dw[WS_C + 0], t01 = dw[WS_C + 1];
  #pragma unroll
  for (int e = 0; e < 32; ++e) {
    t00 += qreg[e] * dw[WS_U + e];
    t01 += qreg[e] * dw[WS_U + 32 + e];
  }
  float wv0[32], wv1[32];
  #pragma unroll
  for (int e2 = 0; e2 < 32; ++e2) {
    wv0[e2] = dw[WS_UB + e2];
    wv1[e2] = dw[WS_UB + 32 + e2];
  }
  #pragma unroll
  for (int e = 0; e < 32; ++e) {
    const float qe = qreg[e];
    #pragma unroll
    for (int e2 = 0; e2 < 32; ++e2) {
      wv0[e2] += qe * dw[WS_M0 + e * 32 + e2];
      wv1[e2] += qe * dw[WS_M0 + 1024 + e * 32 + e2];
    }
  }
  #pragma unroll
  for (int s = 0; s < SS; ++s) gw[s] = __expf(-10.0f * gw[s]);

  // ---- K pipeline: slice u=s+1 in buf((s+1)&1); issue u+2 after consume ----
  float qk0[SS], qk1[SS];
  #pragma unroll
  for (int s = 0; s < SS; ++s) {
    const int b = (s + 1) & 1;
    asm volatile("s_waitcnt vmcnt(8)" ::: "memory");
    float4 ch[8];
    #pragma unroll
    for (int j = 0; j < 8; ++j) ch[j] = kt[b][(l << 3) | (j ^ c)];
    float a0 = t00, a1 = t01;
    #pragma unroll
    for (int j = 0; j < 8; ++j) {
      a0 += wv0[4*j]*ch[j].x + wv0[4*j+1]*ch[j].y + wv0[4*j+2]*ch[j].z + wv0[4*j+3]*ch[j].w;
      a1 += wv1[4*j]*ch[j].x + wv1[4*j+1]*ch[j].y + wv1[4*j+2]*ch[j].z + wv1[4*j+3]*ch[j].w;
    }
    qk0[s] = a0 * gw[s]; qk1[s] = a1 * gw[s];
    if (s + 2 <= SS - 1) {       // s<=6: K slice s+2
      #pragma unroll
      for (int i = 0; i < 8; ++i)
        load16(ks + (s + 2) * EE + i * (8 * SS * EE), &kt[b][i * 64]);
    } else {                      // s=7 -> V0, s=8 -> V1
      const int v2 = s + 2 - SS;
      #pragma unroll
      for (int i = 0; i < 8; ++i)
        load16(vsrc + v2 * EE + i * (8 * SS * EE), &kt[b][i * 64]);
    }
  }

  // ---- softmax over s per head (gw already folded) ----
  float p0[SS], p1[SS];
  {
    float m0 = -1e30f, m1 = -1e30f;
    #pragma unroll
    for (int s = 0; s < SS; ++s) {
      m0 = fmaxf(m0, qk0[s]); m1 = fmaxf(m1, qk1[s]);
    }
    float l0 = 0.f, l1 = 0.f;
    #pragma unroll
    for (int s = 0; s < SS; ++s) {
      p0[s] = __expf(qk0[s] - m0); l0 += p0[s];
      p1[s] = __expf(qk1[s] - m1); l1 += p1[s];
    }
    const float r0 = 1.f / l0, r1 = 1.f / l1;
    #pragma unroll
    for (int s = 0; s < SS; ++s) { p0[s] *= r0; p1[s] *= r1; }
  }

  // ---- V pipeline: slice u=s+10 in buf(s&1); V0/V1 already in flight ----
  float vb0[32], vb1[32];
  #pragma unroll
  for (int e = 0; e < 32; ++e) { vb0[e] = 0.f; vb1[e] = 0.f; }
  #pragma unroll
  for (int s = 0; s < SS; ++s) {
    const int b = s & 1;
    if (s == SS - 1) asm volatile("s_waitcnt vmcnt(0)" ::: "memory");
    else             asm volatile("s_waitcnt vmcnt(8)" ::: "memory");
    float4 ch[8];
    #pragma unroll
    for (int j = 0; j < 8; ++j) ch[j] = kt[b][(l << 3) | (j ^ c)];
    const float w0 = p0[s], w1 = p1[s];
    #pragma unroll
    for (int j = 0; j < 8; ++j) {
      vb0[4*j]   += w0 * ch[j].x; vb0[4*j+1] += w0 * ch[j].y;
      vb0[4*j+2] += w0 * ch[j].z; vb0[4*j+3] += w0 * ch[j].w;
      vb1[4*j]   += w1 * ch[j].x; vb1[4*j+1] += w1 * ch[j].y;
      vb1[4*j+2] += w1 * ch[j].z; vb1[4*j+3] += w1 * ch[j].w;
    }
    if (s + 2 < SS) {
      #pragma unroll
      for (int i = 0; i < 8; ++i)
        load16(vsrc + (s + 2) * EE + i * (8 * SS * EE), &kt[b][i * 64]);
    }
  }

  // ---- fused out-proj ----
  float o[32];
  #pragma unroll
  for (int f = 0; f < 32; ++f) o[f] = dw[WS_BO2 + f];
  #pragma unroll
  for (int e = 0; e < 32; ++e) {
    const float x0 = vb0[e], x1 = vb1[e];
    #pragma unroll
    for (int f = 0; f < 32; ++f) {
      o[f] += x0 * dw[WS_PT0 + e * 32 + f];
      o[f] += x1 * dw[WS_PT0 + 1024 + e * 32 + f];
    }
  }

  // ---- store: 128B contiguous per lane ----
  {
    float4* op = (float4*)(out + (rb + l) * EE);
    #pragma unroll
    for (int i = 0; i < 8; ++i)
      op[i] = make_float4(o[4*i], o[4*i+1], o[4*i+2], o[4*i+3]);
  }
}

extern "C" void kernel_launch(void* const* d_in, const int* in_sizes, int n_in,
                              void* d_out, int out_size, void* d_ws, size_t ws_size,
                              hipStream_t stream) {
  const float* query = (const float*)d_in[0];
  const float* key   = (const float*)d_in[1];
  const float* value = (const float*)d_in[2];
  const float* gauss = (const float*)d_in[3];
  const float* ipw   = (const float*)d_in[4];
  const float* ipb   = (const float*)d_in[5];
  const float* opw   = (const float*)d_in[6];
  const float* opb   = (const float*)d_in[7];
  float* out = (float*)d_out;
  float* dw  = (float*)d_ws;   // needs 4258 floats (~17 KB)

  const int n = in_sizes[0] / EE;  // 262144 batches
  gauss_prep_kernel<<<1, PTPB, 0, stream>>>(ipw, ipb, opw, opb, dw);
  gauss_attn_kernel<<<n / ATPB, ATPB, 0, stream>>>(query, key, value, gauss, dw, out);
}